// Round 11
// baseline (89.237 us; speedup 1.0000x reference)
//
#include <hip/hip_runtime.h>
#include <math.h>

#define N_EXP 64
#define TOPK 8
#define TOPK_G 4
#define D_DIM 2048
#define BM 64
#define WAVES 8
#define THREADS 512
#define KHALF 1024
#define KW (KHALF / WAVES)   // 128 k per wave
#define BK 8                 // k per W-staged chunk
#define NCHUNK (KW / BK)     // 16
#define S_TOT 16384

// kernel 1: GEMM partials. R8 skeleton, but x fragments now load GLOBAL->REG
// directly (no LDS round-trip for x): LDS carries only W (2 b128 reads +
// staging writes per k) -> LDS pipe demand drops ~2x below the FMA floor.
// Each lane loads its 8 rows' float4 per 4-k group; 8 lanes with equal lm
// issue identical addresses (coalescer dedups); each 64B x-line is consumed
// across exactly 4 groups. W staging/reduction/store verbatim R8.
__launch_bounds__(THREADS)
__global__ void gemm_half_kernel(const float* __restrict__ x,
                                 const float* __restrict__ W,
                                 float* __restrict__ part)
{
    __shared__ float smem[8192];   // 32 KB: W dbuf overlay + reduction overlay

    const int tid  = threadIdx.x;
    const int wave = tid >> 6;
    const int lane = tid & 63;
    const int lm   = lane >> 3;   // rows lm*8+i
    const int ln   = lane & 7;    // experts ln*8+j
    const int rb   = blockIdx.x & 255;   // row-block (major)
    const int kh   = blockIdx.x >> 8;    // k-half
    const int row0 = rb * BM;
    const int wb   = wave * 1024;        // W dbuf base (2 x 512 floats)

    const int lr2 = lane >> 1;          // 0..31: expert row for W loads
    const int lk2 = (lane & 1) * 4;     // k-quad within chunk
    const int kbase = kh * KHALF + wave * KW;

    // W global sources (line-dense, R8-proven)
    const float* wq  = W + (size_t)lr2 * D_DIM + kbase + lk2;
    const float* wq2 = wq + (size_t)32 * D_DIM;
    // x base for this lane's row group
    const float* xr = x + (size_t)(row0 + lm * 8) * D_DIM + kbase;

    float acc[8][8];
#pragma unroll
    for (int i = 0; i < 8; ++i)
#pragma unroll
        for (int j = 0; j < 8; ++j) acc[i][j] = 0.f;

    float4 gw0, gw1;

#define LOADW(c) do { \
        gw0 = *(const float4*)(wq  + (c) * BK); \
        gw1 = *(const float4*)(wq2 + (c) * BK); \
    } while (0)

    // scatter to [k][expert]; banks = lr2 (2 lanes each): conflict-free
#define STOREW(p) do { \
        const int b = wb + (p) * 512 + lk2 * 64 + lr2; \
        smem[b +   0] = gw0.x; smem[b +  64] = gw0.y; \
        smem[b + 128] = gw0.z; smem[b + 192] = gw0.w; \
        smem[b +  32] = gw1.x; smem[b +  96] = gw1.y; \
        smem[b + 160] = gw1.z; smem[b + 224] = gw1.w; \
    } while (0)

    // prologue: chunk 0 -> buf0; chunk 1 -> regs
    LOADW(0);
    STOREW(0);
    LOADW(1);

    for (int c = 0; c < NCHUNK; ++c) {
        if (c + 1 < NCHUNK) STOREW((c + 1) & 1);
        if (c + 2 < NCHUNK) LOADW(c + 2);
        const int cw = wb + (c & 1) * 512;
#pragma unroll
        for (int g = 0; g < 2; ++g) {
            // x fragment: 8 rows x 4 k, global -> regs
            float4 fxr[8];
#pragma unroll
            for (int i = 0; i < 8; ++i)
                fxr[i] = *(const float4*)(xr + (size_t)i * D_DIM + c * BK + g * 4);
#pragma unroll
            for (int kk = 0; kk < 4; ++kk) {
                float fw[8];
                *(float4*)&fw[0] = *(const float4*)&smem[cw + (g * 4 + kk) * 64 + ln * 8];
                *(float4*)&fw[4] = *(const float4*)&smem[cw + (g * 4 + kk) * 64 + ln * 8 + 4];
#pragma unroll
                for (int i = 0; i < 8; ++i) {
                    const float xv = ((const float*)&fxr[i])[kk];
#pragma unroll
                    for (int j = 0; j < 8; ++j)
                        acc[i][j] = fmaf(xv, fw[j], acc[i][j]);
                }
            }
        }
    }
#undef LOADW
#undef STOREW

    // cross-wave k-reduction: 4 rounds x 2 writer waves into part[2][64][64]
    // (R4/R8-proven, verbatim)
    float red[8];
#pragma unroll
    for (int j = 0; j < 8; ++j) red[j] = 0.f;
    const int r2 = tid >> 3;          // 0..63
    const int e0 = (tid & 7) * 8;
    const int rsw = 4 * (r2 >> 3);

    for (int rj = 0; rj < 4; ++rj) {
        __syncthreads(); // rj=0: GEMM LDS traffic done; else prior reads done
        if ((wave >> 1) == rj) {
            const int p = wave & 1;
#pragma unroll
            for (int i = 0; i < 8; ++i) {
                const int r = lm * 8 + i;
#pragma unroll
                for (int q = 0; q < 2; ++q) {
                    const int ec = (ln * 8 + q * 4 + 4 * lm) & 63; // writer swizzle
                    *(float4*)&smem[p * 4096 + r * 64 + ec] =
                        make_float4(acc[i][q*4+0], acc[i][q*4+1],
                                    acc[i][q*4+2], acc[i][q*4+3]);
                }
            }
        }
        __syncthreads();
#pragma unroll
        for (int p = 0; p < 2; ++p) {
#pragma unroll
            for (int q = 0; q < 2; ++q) {
                const int ec = (e0 + q * 4 + rsw) & 63;
                const float4 v = *(const float4*)&smem[p * 4096 + r2 * 64 + ec];
                red[q*4+0] += v.x; red[q*4+1] += v.y;
                red[q*4+2] += v.z; red[q*4+3] += v.w;
            }
        }
    }

    float* dst = part + ((size_t)kh * S_TOT + row0 + r2) * N_EXP + e0;
    *(float4*)(dst)     = make_float4(red[0], red[1], red[2], red[3]);
    *(float4*)(dst + 4) = make_float4(red[4], red[5], red[6], red[7]);
}

// kernel 2: sum halves + sigmoid + grouped top-k. R7/R8-proven verbatim.
__global__ void select_kernel(const float* __restrict__ part,
                              const float* __restrict__ bias,
                              float* __restrict__ out_idx,
                              float* __restrict__ out_w)
{
    __shared__ float sc[32 * 68];
    __shared__ float bs[64];

    const int tid = threadIdx.x;
    const int rg  = tid >> 3;     // row within block 0..31
    const int sl  = tid & 7;      // sublane = expert-group (EPG==8)
    const int row = blockIdx.x * 32 + rg;

    if (tid < 64) bs[tid] = bias[tid];

    const float* p0 = part + (size_t)row * N_EXP + sl * 8;
    const float* p1 = p0 + (size_t)S_TOT * N_EXP;
    {
        float4 a0 = *(const float4*)(p0);
        float4 a1 = *(const float4*)(p0 + 4);
        float4 b0 = *(const float4*)(p1);
        float4 b1 = *(const float4*)(p1 + 4);
        sc[rg * 68 + sl * 8 + 0] = 1.0f / (1.0f + expf(-(a0.x + b0.x)));
        sc[rg * 68 + sl * 8 + 1] = 1.0f / (1.0f + expf(-(a0.y + b0.y)));
        sc[rg * 68 + sl * 8 + 2] = 1.0f / (1.0f + expf(-(a0.z + b0.z)));
        sc[rg * 68 + sl * 8 + 3] = 1.0f / (1.0f + expf(-(a0.w + b0.w)));
        sc[rg * 68 + sl * 8 + 4] = 1.0f / (1.0f + expf(-(a1.x + b1.x)));
        sc[rg * 68 + sl * 8 + 5] = 1.0f / (1.0f + expf(-(a1.y + b1.y)));
        sc[rg * 68 + sl * 8 + 6] = 1.0f / (1.0f + expf(-(a1.z + b1.z)));
        sc[rg * 68 + sl * 8 + 7] = 1.0f / (1.0f + expf(-(a1.w + b1.w)));
    }
    __syncthreads();

    float bsc[8];
    float gm = -INFINITY;
#pragma unroll
    for (int j = 0; j < 8; ++j) {
        bsc[j] = sc[rg * 68 + sl * 8 + j] + bs[sl * 8 + j];
        gm = fmaxf(gm, bsc[j]);
    }

    int grank = 0;
#pragma unroll
    for (int s = 1; s < 8; ++s) {
        float og = __shfl_xor(gm, s, 8);
        int   osl = sl ^ s;
        if (og > gm || (og == gm && osl < sl)) ++grank;
    }
    unsigned alive = (grank < TOPK_G) ? 0xFFu : 0u;

    float wsum = 0.f;
    float myw = 0.f;
    const int orow = row * TOPK;
    for (int k = 0; k < TOPK; ++k) {
        float bv = -INFINITY; int be = 9999;
#pragma unroll
        for (int j = 0; j < 8; ++j) {
            if (alive & (1u << j)) {
                if (bsc[j] > bv) { bv = bsc[j]; be = sl * 8 + j; }
            }
        }
#pragma unroll
        for (int s = 1; s < 8; s <<= 1) {
            float ov = __shfl_xor(bv, s, 8);
            int   oe = __shfl_xor(be, s, 8);
            if (ov > bv || (ov == bv && oe < be)) { bv = ov; be = oe; }
        }
        const float wr = sc[rg * 68 + be];   // broadcast read of raw score
        wsum += wr;
        if ((be >> 3) == sl) alive &= ~(1u << (be & 7));
        if (sl == k) { out_idx[orow + k] = (float)be; myw = wr; }
    }
    const float inv = 1.0f / (wsum + 1e-20f);
    out_w[orow + sl] = myw * inv;
}

extern "C" void kernel_launch(void* const* d_in, const int* in_sizes, int n_in,
                              void* d_out, int out_size, void* d_ws, size_t ws_size,
                              hipStream_t stream) {
    const float* x    = (const float*)d_in[0];
    const float* W    = (const float*)d_in[1];
    const float* bias = (const float*)d_in[2];
    float* out  = (float*)d_out;
    float* part = (float*)d_ws; // 2*16384*64*4 = 8 MB scratch

    hipLaunchKernelGGL(gemm_half_kernel, dim3((S_TOT / BM) * 2), dim3(THREADS), 0, stream,
                       x, W, part);
    hipLaunchKernelGGL(select_kernel, dim3(S_TOT / 32), dim3(256), 0, stream,
                       part, bias, out, out + S_TOT * TOPK);
}

// Round 12
// 82.904 us; speedup vs baseline: 1.0764x; 1.0764x over previous
//
#include <hip/hip_runtime.h>
#include <math.h>

#define N_EXP 64
#define TOPK 8
#define TOPK_G 4
#define D_DIM 2048
#define BM 64
#define WAVES 8
#define THREADS 512
#define KHALF 1024
#define KW (KHALF / WAVES)   // 128 k per wave
#define BK 8                 // k per staged chunk
#define NCHUNK (KW / BK)     // 16
#define S_TOT 16384

// kernel 1: GEMM partials. R8-proven skeleton (83.2us, VGPR 96). ONLY change:
// explicit frag double-buffer — k+1's 4 ds_read_b128 issued BEFORE k's 64
// FMAs (two frag sets, compile-time alternation), k=0 read hoisted above the
// staging ds_writes. Restores LDS-read/FMA overlap within each wave.
__launch_bounds__(THREADS)
__global__ void gemm_half_kernel(const float* __restrict__ x,
                                 const float* __restrict__ W,
                                 float* __restrict__ part)
{
    __shared__ float smem[16384];

    const int tid  = threadIdx.x;
    const int wave = tid >> 6;
    const int lane = tid & 63;
    const int lm   = lane >> 3;   // rows lm*8+i
    const int ln   = lane & 7;    // experts ln*8+j
    const int rb   = blockIdx.x & 255;   // row-block (major)
    const int kh   = blockIdx.x >> 8;    // k-half
    const int row0 = rb * BM;
    const int xb   = wave * 2048;

    const int lr2 = lane >> 1;          // 0..31 row/expert for loads
    const int lk2 = (lane & 1) * 4;     // k-quad within chunk
    const int kbase = kh * KHALF + wave * KW;

    const float* xq  = x + (size_t)(row0 + lr2) * D_DIM + kbase + lk2;
    const float* wq  = W + (size_t)lr2 * D_DIM + kbase + lk2;
    const float* xq2 = xq + (size_t)32 * D_DIM;
    const float* wq2 = wq + (size_t)32 * D_DIM;

    float acc[8][8];
#pragma unroll
    for (int i = 0; i < 8; ++i)
#pragma unroll
        for (int j = 0; j < 8; ++j) acc[i][j] = 0.f;

    float4 gx0, gx1, gw0, gw1;

#define LOADG(c) do { \
        gx0 = *(const float4*)(xq  + (c) * BK); \
        gx1 = *(const float4*)(xq2 + (c) * BK); \
        gw0 = *(const float4*)(wq  + (c) * BK); \
        gw1 = *(const float4*)(wq2 + (c) * BK); \
    } while (0)

    // scatter to [k][row] (x) / [k][expert] (W); banks = lr2, 2 lanes each: free
#define STOREG(p) do { \
        const int a = xb + (p) * 1024 + lk2 * 64 + lr2; \
        smem[a +   0] = gx0.x; smem[a +  64] = gx0.y; \
        smem[a + 128] = gx0.z; smem[a + 192] = gx0.w; \
        smem[a +  32] = gx1.x; smem[a +  96] = gx1.y; \
        smem[a + 160] = gx1.z; smem[a + 224] = gx1.w; \
        const int b = a + 512; \
        smem[b +   0] = gw0.x; smem[b +  64] = gw0.y; \
        smem[b + 128] = gw0.z; smem[b + 192] = gw0.w; \
        smem[b +  32] = gw1.x; smem[b +  96] = gw1.y; \
        smem[b + 160] = gw1.z; smem[b + 224] = gw1.w; \
    } while (0)

    // frag load for k-step kk of current buffer into slot s (compile-time s,kk)
#define LDFRAG(s, cb, kk) do { \
        *(float4*)&fx[s][0] = *(const float4*)&smem[(cb) + (kk) * 64 + lm * 8]; \
        *(float4*)&fx[s][4] = *(const float4*)&smem[(cb) + (kk) * 64 + lm * 8 + 4]; \
        *(float4*)&fw[s][0] = *(const float4*)&smem[(cb) + 512 + (kk) * 64 + ln * 8]; \
        *(float4*)&fw[s][4] = *(const float4*)&smem[(cb) + 512 + (kk) * 64 + ln * 8 + 4]; \
    } while (0)

    // prologue: chunk 0 -> buf0; chunk 1 -> regs
    LOADG(0);
    STOREG(0);
    LOADG(1);

    float fx[2][8], fw[2][8];

    for (int c = 0; c < NCHUNK; ++c) {
        const int cb = xb + (c & 1) * 1024;
        // hoist k=0 frag read ABOVE staging writes (in-order lgkm queue:
        // otherwise its wait drains 32 ds_writes first)
        LDFRAG(0, cb, 0);
        if (c + 1 < NCHUNK) STOREG((c + 1) & 1);
        if (c + 2 < NCHUNK) LOADG(c + 2);
#pragma unroll
        for (int k = 0; k < BK; ++k) {
            const int cur = k & 1;
            const int nxt = cur ^ 1;
            if (k + 1 < BK) LDFRAG(nxt, cb, k + 1);  // issue BEFORE k's FMAs
#pragma unroll
            for (int i = 0; i < 8; ++i)
#pragma unroll
                for (int j = 0; j < 8; ++j)
                    acc[i][j] = fmaf(fx[cur][i], fw[cur][j], acc[i][j]);
        }
    }
#undef LOADG
#undef STOREG
#undef LDFRAG

    // cross-wave k-reduction: 4 rounds x 2 writer waves into part[2][64][64]
    // (R4/R8-proven, verbatim)
    float red[8];
#pragma unroll
    for (int j = 0; j < 8; ++j) red[j] = 0.f;
    const int r2 = tid >> 3;          // 0..63
    const int e0 = (tid & 7) * 8;
    const int rsw = 4 * (r2 >> 3);

    for (int rj = 0; rj < 4; ++rj) {
        __syncthreads(); // rj=0: GEMM LDS traffic done; else prior reads done
        if ((wave >> 1) == rj) {
            const int p = wave & 1;
#pragma unroll
            for (int i = 0; i < 8; ++i) {
                const int r = lm * 8 + i;
#pragma unroll
                for (int q = 0; q < 2; ++q) {
                    const int ec = (ln * 8 + q * 4 + 4 * lm) & 63; // writer swizzle
                    *(float4*)&smem[p * 4096 + r * 64 + ec] =
                        make_float4(acc[i][q*4+0], acc[i][q*4+1],
                                    acc[i][q*4+2], acc[i][q*4+3]);
                }
            }
        }
        __syncthreads();
#pragma unroll
        for (int p = 0; p < 2; ++p) {
#pragma unroll
            for (int q = 0; q < 2; ++q) {
                const int ec = (e0 + q * 4 + rsw) & 63;
                const float4 v = *(const float4*)&smem[p * 4096 + r2 * 64 + ec];
                red[q*4+0] += v.x; red[q*4+1] += v.y;
                red[q*4+2] += v.z; red[q*4+3] += v.w;
            }
        }
    }

    float* dst = part + ((size_t)kh * S_TOT + row0 + r2) * N_EXP + e0;
    *(float4*)(dst)     = make_float4(red[0], red[1], red[2], red[3]);
    *(float4*)(dst + 4) = make_float4(red[4], red[5], red[6], red[7]);
}

// kernel 2: sum halves + sigmoid + grouped top-k. R7/R8-proven verbatim.
__global__ void select_kernel(const float* __restrict__ part,
                              const float* __restrict__ bias,
                              float* __restrict__ out_idx,
                              float* __restrict__ out_w)
{
    __shared__ float sc[32 * 68];
    __shared__ float bs[64];

    const int tid = threadIdx.x;
    const int rg  = tid >> 3;     // row within block 0..31
    const int sl  = tid & 7;      // sublane = expert-group (EPG==8)
    const int row = blockIdx.x * 32 + rg;

    if (tid < 64) bs[tid] = bias[tid];

    const float* p0 = part + (size_t)row * N_EXP + sl * 8;
    const float* p1 = p0 + (size_t)S_TOT * N_EXP;
    {
        float4 a0 = *(const float4*)(p0);
        float4 a1 = *(const float4*)(p0 + 4);
        float4 b0 = *(const float4*)(p1);
        float4 b1 = *(const float4*)(p1 + 4);
        sc[rg * 68 + sl * 8 + 0] = 1.0f / (1.0f + expf(-(a0.x + b0.x)));
        sc[rg * 68 + sl * 8 + 1] = 1.0f / (1.0f + expf(-(a0.y + b0.y)));
        sc[rg * 68 + sl * 8 + 2] = 1.0f / (1.0f + expf(-(a0.z + b0.z)));
        sc[rg * 68 + sl * 8 + 3] = 1.0f / (1.0f + expf(-(a0.w + b0.w)));
        sc[rg * 68 + sl * 8 + 4] = 1.0f / (1.0f + expf(-(a1.x + b1.x)));
        sc[rg * 68 + sl * 8 + 5] = 1.0f / (1.0f + expf(-(a1.y + b1.y)));
        sc[rg * 68 + sl * 8 + 6] = 1.0f / (1.0f + expf(-(a1.z + b1.z)));
        sc[rg * 68 + sl * 8 + 7] = 1.0f / (1.0f + expf(-(a1.w + b1.w)));
    }
    __syncthreads();

    float bsc[8];
    float gm = -INFINITY;
#pragma unroll
    for (int j = 0; j < 8; ++j) {
        bsc[j] = sc[rg * 68 + sl * 8 + j] + bs[sl * 8 + j];
        gm = fmaxf(gm, bsc[j]);
    }

    int grank = 0;
#pragma unroll
    for (int s = 1; s < 8; ++s) {
        float og = __shfl_xor(gm, s, 8);
        int   osl = sl ^ s;
        if (og > gm || (og == gm && osl < sl)) ++grank;
    }
    unsigned alive = (grank < TOPK_G) ? 0xFFu : 0u;

    float wsum = 0.f;
    float myw = 0.f;
    const int orow = row * TOPK;
    for (int k = 0; k < TOPK; ++k) {
        float bv = -INFINITY; int be = 9999;
#pragma unroll
        for (int j = 0; j < 8; ++j) {
            if (alive & (1u << j)) {
                if (bsc[j] > bv) { bv = bsc[j]; be = sl * 8 + j; }
            }
        }
#pragma unroll
        for (int s = 1; s < 8; s <<= 1) {
            float ov = __shfl_xor(bv, s, 8);
            int   oe = __shfl_xor(be, s, 8);
            if (ov > bv || (ov == bv && oe < be)) { bv = ov; be = oe; }
        }
        const float wr = sc[rg * 68 + be];   // broadcast read of raw score
        wsum += wr;
        if ((be >> 3) == sl) alive &= ~(1u << (be & 7));
        if (sl == k) { out_idx[orow + k] = (float)be; myw = wr; }
    }
    const float inv = 1.0f / (wsum + 1e-20f);
    out_w[orow + sl] = myw * inv;
}

extern "C" void kernel_launch(void* const* d_in, const int* in_sizes, int n_in,
                              void* d_out, int out_size, void* d_ws, size_t ws_size,
                              hipStream_t stream) {
    const float* x    = (const float*)d_in[0];
    const float* W    = (const float*)d_in[1];
    const float* bias = (const float*)d_in[2];
    float* out  = (float*)d_out;
    float* part = (float*)d_ws; // 2*16384*64*4 = 8 MB scratch

    hipLaunchKernelGGL(gemm_half_kernel, dim3((S_TOT / BM) * 2), dim3(THREADS), 0, stream,
                       x, W, part);
    hipLaunchKernelGGL(select_kernel, dim3(S_TOT / 32), dim3(256), 0, stream,
                       part, bias, out, out + S_TOT * TOPK);
}